// Round 4
// baseline (56.772 us; speedup 1.0000x reference)
//
#include <hip/hip_runtime.h>

#define NCLS 1024
#define EPS_C 1e-5f
#define LOSS_BLOCKS 2048   // 2048 blocks * 4 waves * 8 rows/wave = 65536 rows

// ---------------- helpers ----------------
__device__ __forceinline__ float sumexp16(float4 a, float4 b, float4 c, float4 d) {
    return __expf(a.x) + __expf(a.y) + __expf(a.z) + __expf(a.w)
         + __expf(b.x) + __expf(b.y) + __expf(b.z) + __expf(b.w)
         + __expf(c.x) + __expf(c.y) + __expf(c.z) + __expf(c.w)
         + __expf(d.x) + __expf(d.y) + __expf(d.z) + __expf(d.w);
}

// ---------------- Kernel 1: streaming sum-exp + unweighted focal term ----------------
// 8 rows per wave; accumulates f_i = -(1-pt)^2*logpt into per-class bins (no weights needed).
__global__ __launch_bounds__(256) void loss_kernel(const float* __restrict__ inp,
                                                   const int* __restrict__ tgt,
                                                   float* __restrict__ fbins,
                                                   unsigned int* __restrict__ cbins,
                                                   int B) {
    const int wave  = threadIdx.x >> 6;
    const int lane  = threadIdx.x & 63;
    const int gwave = blockIdx.x * 4 + wave;
    const int base  = gwave * 8;
    if (base >= B) return;

    if (base + 8 <= B) {
        float s[8];
        const float4* rp = (const float4*)(inp + (size_t)base * NCLS);
        #pragma unroll
        for (int rr = 0; rr < 8; ++rr) {
            float4 a0 = rp[lane];
            float4 a1 = rp[lane + 64];
            float4 a2 = rp[lane + 128];
            float4 a3 = rp[lane + 192];
            s[rr] = sumexp16(a0, a1, a2, a3);
            rp += NCLS / 4;
        }
        // one butterfly, 8 independent chains
        #pragma unroll
        for (int off = 32; off > 0; off >>= 1) {
            #pragma unroll
            for (int rr = 0; rr < 8; ++rr) s[rr] += __shfl_xor(s[rr], off);
        }
        // lane r (r<8) takes row base+r
        float myS = s[0];
        #pragma unroll
        for (int rr = 1; rr < 8; ++rr) myS = (lane == rr) ? s[rr] : myS;

        if (lane < 8) {
            const int row = base + lane;
            const int t = tgt[row] & (NCLS - 1);
            const float xt = inp[(size_t)row * NCLS + t];   // L2-hot gather
            const float lp = xt - __logf(myS);
            const float p  = __expf(lp);
            const float o  = 1.0f - p;
            const float f  = -o * o * lp;
            atomicAdd(&fbins[t], f);
            atomicAdd(&cbins[t], 1u);
        }
    } else {
        // generic tail (dead at B=65536)
        for (int r = base; r < B && r < base + 8; ++r) {
            const float4* rp = (const float4*)(inp + (size_t)r * NCLS);
            float4 a0 = rp[lane], a1 = rp[lane + 64], a2 = rp[lane + 128], a3 = rp[lane + 192];
            float s0 = sumexp16(a0, a1, a2, a3);
            #pragma unroll
            for (int off = 32; off > 0; off >>= 1) s0 += __shfl_xor(s0, off);
            if (lane == 0) {
                const int t = tgt[r] & (NCLS - 1);
                const float xt = inp[(size_t)r * NCLS + t];
                const float lp = xt - __logf(s0);
                const float p  = __expf(lp);
                const float o  = 1.0f - p;
                atomicAdd(&fbins[t], -o * o * lp);
                atomicAdd(&cbins[t], 1u);
            }
        }
    }
}

// ---------------- Kernel 2: weights + weighted total (single block) ----------------
__global__ __launch_bounds__(1024) void finalize_kernel(const float* __restrict__ fbins,
                                                        const unsigned int* __restrict__ cbins,
                                                        float* __restrict__ out, float invB) {
    __shared__ float sred[16];
    const int tid = threadIdx.x;
    const unsigned int cu = cbins[tid];
    const float c = (float)cu;

    // min over ALL counts (including zeros), matching reference semantics
    float m = c;
    #pragma unroll
    for (int off = 32; off > 0; off >>= 1) m = fminf(m, __shfl_xor(m, off));
    if ((tid & 63) == 0) sred[tid >> 6] = m;
    __syncthreads();
    if (tid == 0) {
        float mm = sred[0];
        #pragma unroll
        for (int i = 1; i < 16; ++i) mm = fminf(mm, sred[i]);
        sred[0] = mm;
    }
    __syncthreads();
    const float cmin = sred[0];
    __syncthreads();

    // contribution: fbins[c] * (cmin/c + eps); zero-count classes contribute 0
    float v = (cu > 0u) ? fbins[tid] * (cmin / c + EPS_C) : 0.0f;
    #pragma unroll
    for (int off = 32; off > 0; off >>= 1) v += __shfl_xor(v, off);
    if ((tid & 63) == 0) sred[tid >> 6] = v;
    __syncthreads();
    if (tid == 0) {
        float t = 0.0f;
        #pragma unroll
        for (int i = 0; i < 16; ++i) t += sred[i];
        out[0] = t * invB;
    }
}

extern "C" void kernel_launch(void* const* d_in, const int* in_sizes, int n_in,
                              void* d_out, int out_size, void* d_ws, size_t ws_size,
                              hipStream_t stream) {
    const float* inp = (const float*)d_in[0];
    const int*   tgt = (const int*)d_in[1];
    const int B = in_sizes[1];          // 65536

    unsigned int* cbins = (unsigned int*)d_ws;                 // 1024 u32
    float*        fbins = (float*)((char*)d_ws + 4096);        // 1024 f32

    // zero both bin arrays (captured; replays re-zero)
    hipMemsetAsync(d_ws, 0, 8192, stream);

    loss_kernel<<<LOSS_BLOCKS, 256, 0, stream>>>(inp, tgt, fbins, cbins, B);
    finalize_kernel<<<1, 1024, 0, stream>>>(fbins, cbins, (float*)d_out, 1.0f / (float)B);
}